// Round 5
// baseline (551.244 us; speedup 1.0000x reference)
//
#include <hip/hip_runtime.h>
#include <hip/hip_bf16.h>
#include <cmath>

typedef unsigned short u16;
typedef unsigned char u8;
typedef unsigned int u32;
typedef __attribute__((ext_vector_type(8))) _Float16 f16x8;
typedef __attribute__((ext_vector_type(4))) float f32x4;

__device__ __forceinline__ float bf2f(u16 v) {
    union { u32 u; float f; } c; c.u = (u32)v << 16; return c.f;
}
__device__ __forceinline__ u16 f2bf(float f) {
    union { float f; u32 u; } c; c.f = f;
    u32 u = c.u;
    u += 0x7FFF + ((u >> 16) & 1);
    return (u16)(u >> 16);
}
__device__ __forceinline__ u16 f2h(float f) {
    _Float16 h = (_Float16)f; u16 r; __builtin_memcpy(&r, &h, 2); return r;
}
__device__ __forceinline__ float h2f(u16 b) {
    _Float16 h; __builtin_memcpy(&h, &b, 2); return (float)h;
}

// async global->LDS DMA, 16B/lane; LDS dest = wave-uniform base + lane*16
__device__ __forceinline__ void gld_lds16(const void* g, void* l) {
    __builtin_amdgcn_global_load_lds(
        (const __attribute__((address_space(1))) void*)g,
        (__attribute__((address_space(3))) void*)l, 16, 0, 0);
}

// counted-vmcnt pipeline primitives (T4): never drain to 0 in the main loop
#define VMCNT8()  asm volatile("s_waitcnt vmcnt(8)" ::: "memory")
#define VMCNT0()  asm volatile("s_waitcnt vmcnt(0)" ::: "memory")
#define SBAR()    asm volatile("s_barrier" ::: "memory")

// ---- dtype sniff: flag=1 if raw u16 stream looks like bf16, 0 if fp32 ----
__global__ __launch_bounds__(256) void sniff_kernel(const u16* __restrict__ x,
                                                    u32* __restrict__ flag) {
    const int t = threadIdx.x;
    int local = 0;
    for (int i = t; i < 4096; i += 256) {
        const int e = (x[i] >> 7) & 0xFF;
        if (e >= 110 && e <= 137) local++;
    }
#pragma unroll
    for (int o = 32; o > 0; o >>= 1) local += __shfl_down(local, o, 64);
    __shared__ int s[4];
    if ((t & 63) == 0) s[t >> 6] = local;
    __syncthreads();
    if (t == 0) {
        const int tot = s[0] + s[1] + s[2] + s[3];
        *flag = (tot >= 3200) ? 1u : 0u;
    }
}

// ==== merged prep: blocks [0,1024) conv_split, [1024,2048) conv_wt,
// [2048] conv_a. ====
__global__ __launch_bounds__(256) void prep_kernel(
    const void* __restrict__ xin, const void* __restrict__ Win,
    const void* __restrict__ ain,
    u16* __restrict__ xhi, u16* __restrict__ xlo,
    u16* __restrict__ WT, u16* __restrict__ aout,
    const u32* __restrict__ flag, int N, int D)
{
    __shared__ u16 tile[64][68];
    const bool isbf = (*flag != 0);
    const int b = blockIdx.x;
    const int t = threadIdx.x;

    if (b < 1024) {
        const long base = (long)b * 8192;
#pragma unroll
        for (int it = 0; it < 8; ++it) {
            const long i = base + (long)(it * 256 + t) * 4;
            float v[4];
            if (isbf) {
                ushort4 u = *(const ushort4*)((const u16*)xin + i);
                v[0] = bf2f(u.x); v[1] = bf2f(u.y); v[2] = bf2f(u.z); v[3] = bf2f(u.w);
            } else {
                float4 f = *(const float4*)((const float*)xin + i);
                v[0] = f.x; v[1] = f.y; v[2] = f.z; v[3] = f.w;
            }
            ushort4 hi, lo;
            u16* hp = &hi.x; u16* lp = &lo.x;
#pragma unroll
            for (int k = 0; k < 4; ++k) {
                _Float16 h = (_Float16)v[k];
                u16 hb; __builtin_memcpy(&hb, &h, 2);
                hp[k] = hb;
                lp[k] = f2h(v[k] - (float)h);
            }
            *(ushort4*)(xhi + i) = hi;
            *(ushort4*)(xlo + i) = lo;
        }
    } else if (b < 2048) {
        const int tt = b - 1024;
        const int bc = (tt & 31) * 64;
        const int br = (tt >> 5) * 64;
        const int lr = t >> 4;
        const int lc = (t & 15) * 4;
#pragma unroll
        for (int s = 0; s < 4; ++s) {
            const int r = lr + s * 16;
            float v[4];
            if (isbf) {
                ushort4 u = *(const ushort4*)((const u16*)Win + (size_t)(br + r) * D + bc + lc);
                v[0] = bf2f(u.x); v[1] = bf2f(u.y); v[2] = bf2f(u.z); v[3] = bf2f(u.w);
            } else {
                float4 f = *(const float4*)((const float*)Win + (size_t)(br + r) * D + bc + lc);
                v[0] = f.x; v[1] = f.y; v[2] = f.z; v[3] = f.w;
            }
            tile[r][lc + 0] = f2h(v[0]); tile[r][lc + 1] = f2h(v[1]);
            tile[r][lc + 2] = f2h(v[2]); tile[r][lc + 3] = f2h(v[3]);
        }
        __syncthreads();
#pragma unroll
        for (int s = 0; s < 4; ++s) {
            const int oc = lr + s * 16;
            ushort4 v;
            v.x = tile[lc + 0][oc]; v.y = tile[lc + 1][oc];
            v.z = tile[lc + 2][oc]; v.w = tile[lc + 3][oc];
            *(ushort4*)&WT[(size_t)(bc + oc) * D + br + lc] = v;
        }
    } else {
        for (int i = t; i < 2 * D; i += 256) {
            float v = isbf ? bf2f(((const u16*)ain)[i]) : ((const float*)ain)[i];
            aout[i] = f2h(v);
        }
    }
}

// ==== FUSED: triangle mask (0..527) + h=x@W (528..1039).
// 128x128 tiles, 4 waves, BK=64, double-buffered 64 KB LDS, counted-vmcnt
// pipeline (T4): stage(t+1) issued, vmcnt(8) waits only the OLDER batch,
// raw s_barrier (no drain) -> prefetch stays in flight across the barrier.
// Bank-conflict-free swizzle as verified in R3/R4.
#define NMASK 528
#define MAXFIX 1024
#define MTAU 0.125f
__global__ __launch_bounds__(256, 2) void fused_mask_h(
    const u16* __restrict__ Xhi, const u16* __restrict__ Xlo, int ldx,
    u16* __restrict__ P, int N,
    const void* __restrict__ adj,
    const u16* __restrict__ WT, int D,
    u16* __restrict__ h,
    const u32* __restrict__ dflag)
{
    __shared__ alignas(16) u16 sm[2][2][128 * 64];   // [buf][A/B], 64 KB

    const int tid = threadIdx.x;
    const int wave = tid >> 6, lane = tid & 63;
    const int wr = wave >> 1, wc = wave & 1;          // 2x2 waves over 128x128
    const int q = lane >> 4, mrow = lane & 15;        // mfma frag coords
    const int srow8 = lane >> 3;                      // staging row in 8-row chunk
    const int gslot = (lane & 7) ^ srow8;             // pre-swizzled global slot

    // XCD-aware bijective swizzle (1040 = 8 * 130)
    const int bid = blockIdx.x;
    const int swz = (bid & 7) * 130 + (bid >> 3);

    if (swz < NMASK) {
        // ---- mask: triangle block (bm >= bn) of adj*(x@x^T) > 0 ----
        const int idx = swz;
        int bm = (int)((__builtin_sqrtf(8.0f * idx + 1.0f) - 1.0f) * 0.5f);
        while ((bm + 1) * (bm + 2) / 2 <= idx) ++bm;
        while (bm * (bm + 1) / 2 > idx) --bm;
        const int bn = idx - bm * (bm + 1) / 2;   // bn <= bm

        const u16* Ab = Xhi + (size_t)bm * 128 * ldx;
        const u16* Bb = Xhi + (size_t)bn * 128 * ldx;

        f32x4 acc[4][4] = {};

#define STAGE_M(buf, kt)                                                     \
        {                                                                    \
            _Pragma("unroll")                                                \
            for (int it = 0; it < 4; ++it) {                                 \
                const int c = wave * 4 + it;                                 \
                const int row = c * 8 + srow8;                               \
                const size_t go = (size_t)row * ldx + (kt) + gslot * 8;      \
                gld_lds16(Ab + go, &sm[buf][0][c * 512]);                    \
                gld_lds16(Bb + go, &sm[buf][1][c * 512]);                    \
            }                                                                \
        }

        const int T = ldx >> 6;                 // 32 K-steps
        STAGE_M(0, 0);                          // 8 loads in flight
        for (int t = 0; t < T; ++t) {
            if (t + 1 < T) { STAGE_M((t + 1) & 1, (t + 1) * 64); VMCNT8(); }
            else           { VMCNT0(); }
            SBAR();                             // buf t fully populated
            const int buf = t & 1;
            f16x8 a[2][4], b[2][4];
#pragma unroll
            for (int ks = 0; ks < 2; ++ks)
#pragma unroll
                for (int i = 0; i < 4; ++i) {
                    const int ra = wr * 64 + i * 16 + mrow;
                    const int rb = wc * 64 + i * 16 + mrow;
                    const int sa = ((q + 4 * ks) ^ (mrow & 7)) * 8;
                    a[ks][i] = *(const f16x8*)&sm[buf][0][ra * 64 + sa];
                    b[ks][i] = *(const f16x8*)&sm[buf][1][rb * 64 + sa];
                }
#pragma unroll
            for (int i = 0; i < 4; ++i)
#pragma unroll
                for (int j = 0; j < 4; ++j) {
                    acc[i][j] = __builtin_amdgcn_mfma_f32_16x16x32_f16(
                        a[0][i], b[0][j], acc[i][j], 0, 0, 0);
                    acc[i][j] = __builtin_amdgcn_mfma_f32_16x16x32_f16(
                        a[1][i], b[1][j], acc[i][j], 0, 0, 0);
                }
            SBAR();                             // reads of buf t done
        }
#undef STAGE_M

        const bool isbf = (*dflag != 0);
        const u16* adjB = (const u16*)adj;
        const float* adjF = (const float*)adj;
        const float tau = isbf ? -1.0f : MTAU;   // bf16->f16 exact: no fixup

        // ---- epilogue: sign tile + borderline fixup + masked P writes ----
        u8* sgn = (u8*)sm;                        // 128 x 132 = 16896 B
        u32* list = (u32*)((u8*)sm + 24576);      // MAXFIX u32
        int* cntp = (int*)((u8*)sm + 28672);

        if (tid == 0) *cntp = 0;
#pragma unroll
        for (int i = 0; i < 4; ++i)
#pragma unroll
            for (int j = 0; j < 4; ++j)
#pragma unroll
                for (int r = 0; r < 4; ++r) {
                    const int rl = wr * 64 + i * 16 + q * 4 + r;
                    const int cl = wc * 64 + j * 16 + mrow;
                    const float v = acc[i][j][r];
                    sgn[rl * 132 + cl] = v > 0.f ? (u8)1
                                       : (v < 0.f ? (u8)2 : (u8)0);
                }
        __syncthreads();

#pragma unroll
        for (int i = 0; i < 4; ++i)
#pragma unroll
            for (int j = 0; j < 4; ++j)
#pragma unroll
                for (int r = 0; r < 4; ++r)
                    if (__builtin_fabsf(acc[i][j][r]) < tau) {
                        const int rl = wr * 64 + i * 16 + q * 4 + r;
                        const int cl = wc * 64 + j * 16 + mrow;
                        const int ix = atomicAdd(cntp, 1);
                        if (ix < MAXFIX) list[ix] = (u32)((rl << 8) | cl);
                    }
        __syncthreads();

        const int nfix = (*cntp < MAXFIX) ? *cntp : MAXFIX;
        for (int e = wave; e < nfix; e += 4) {
            const u32 pk = list[e];
            const int rl = (int)(pk >> 8), cl = (int)(pk & 255u);
            const u16* arh = Xhi + (size_t)(bm * 128 + rl) * ldx;
            const u16* arl = Xlo + (size_t)(bm * 128 + rl) * ldx;
            const u16* brh = Xhi + (size_t)(bn * 128 + cl) * ldx;
            const u16* brl = Xlo + (size_t)(bn * 128 + cl) * ldx;
            float ssum = 0.f;
#pragma unroll
            for (int kk = 0; kk < 4; ++kk) {
                const int k = kk * 512 + lane * 8;
                const f16x8 vah = *(const f16x8*)&arh[k];
                const f16x8 val2 = *(const f16x8*)&arl[k];
                const f16x8 vbh = *(const f16x8*)&brh[k];
                const f16x8 vbl = *(const f16x8*)&brl[k];
#pragma unroll
                for (int u = 0; u < 8; ++u)
                    ssum += ((float)vah[u] + (float)val2[u]) *
                            ((float)vbh[u] + (float)vbl[u]);
            }
#pragma unroll
            for (int o = 32; o > 0; o >>= 1) ssum += __shfl_xor(ssum, o, 64);
            if (lane == 0)
                sgn[rl * 132 + cl] = ssum > 0.f ? (u8)1
                                   : (ssum < 0.f ? (u8)2 : (u8)0);
        }
        __syncthreads();

        // normal orientation: coalesced, via sign tile
        {
            const int c = tid & 127;
            const int r0 = tid >> 7;
#pragma unroll 4
            for (int s = 0; s < 64; ++s) {
                const int rr = r0 + 2 * s;
                const u8 s3 = sgn[rr * 132 + c];
                const size_t aidx = (size_t)(bm * 128 + rr) * N + bn * 128 + c;
                const float av = isbf ? bf2f(adjB[aidx]) : adjF[aidx];
                const bool f = (s3 == 1) ? (av > 0.f)
                             : (s3 == 2) ? (av < 0.f) : false;
                P[aidx] = f ? (u16)1 : (u16)0;
            }
        }

        if (bm != bn) {
            // transposed orientation (stride-132 sign reads, conflict-free)
            const int bl_ = tid & 63;
            const int a0 = tid >> 6;
#pragma unroll 4
            for (int s = 0; s < 32; ++s) {
                const int a = a0 + 4 * s;
#pragma unroll
                for (int hb = 0; hb < 2; ++hb) {
                    const int b = bl_ + 64 * hb;
                    const u8 s3 = sgn[b * 132 + a];
                    const size_t aidx = (size_t)(bn * 128 + a) * N + bm * 128 + b;
                    const float av = isbf ? bf2f(adjB[aidx]) : adjF[aidx];
                    const bool f = (s3 == 1) ? (av > 0.f)
                                 : (s3 == 2) ? (av < 0.f) : false;
                    P[aidx] = f ? (u16)1 : (u16)0;
                }
            }
        }
    } else {
        // ---- h = x @ W (NT against WT) ----
        const int j = swz - NMASK;
        const int bn = j & 15;    // D/128 = 16
        const int bm = j >> 4;    // N/128 = 32

        const u16* Ab = Xhi + (size_t)bm * 128 * ldx;
        const u16* Bb = WT + (size_t)bn * 128 * D;

        f32x4 acc[4][4] = {};

#define STAGE_H(buf, kt)                                                     \
        {                                                                    \
            _Pragma("unroll")                                                \
            for (int it = 0; it < 4; ++it) {                                 \
                const int c = wave * 4 + it;                                 \
                const int row = c * 8 + srow8;                               \
                gld_lds16(Ab + (size_t)row * ldx + (kt) + gslot * 8,         \
                          &sm[buf][0][c * 512]);                             \
                gld_lds16(Bb + (size_t)row * D + (kt) + gslot * 8,           \
                          &sm[buf][1][c * 512]);                             \
            }                                                                \
        }

        const int T = D >> 6;
        STAGE_H(0, 0);
        for (int t = 0; t < T; ++t) {
            if (t + 1 < T) { STAGE_H((t + 1) & 1, (t + 1) * 64); VMCNT8(); }
            else           { VMCNT0(); }
            SBAR();
            const int buf = t & 1;
            f16x8 a[2][4], b[2][4];
#pragma unroll
            for (int ks = 0; ks < 2; ++ks)
#pragma unroll
                for (int i = 0; i < 4; ++i) {
                    const int ra = wr * 64 + i * 16 + mrow;
                    const int rb = wc * 64 + i * 16 + mrow;
                    const int sa = ((q + 4 * ks) ^ (mrow & 7)) * 8;
                    a[ks][i] = *(const f16x8*)&sm[buf][0][ra * 64 + sa];
                    b[ks][i] = *(const f16x8*)&sm[buf][1][rb * 64 + sa];
                }
#pragma unroll
            for (int i = 0; i < 4; ++i)
#pragma unroll
                for (int jj = 0; jj < 4; ++jj) {
                    acc[i][jj] = __builtin_amdgcn_mfma_f32_16x16x32_f16(
                        a[0][i], b[0][jj], acc[i][jj], 0, 0, 0);
                    acc[i][jj] = __builtin_amdgcn_mfma_f32_16x16x32_f16(
                        a[1][i], b[1][jj], acc[i][jj], 0, 0, 0);
                }
            SBAR();
        }
#undef STAGE_H

        const int row0 = bm * 128 + wr * 64 + q * 4;
        const int col0 = bn * 128 + wc * 64 + mrow;
#pragma unroll
        for (int i = 0; i < 4; ++i)
#pragma unroll
            for (int jj = 0; jj < 4; ++jj)
#pragma unroll
                for (int r = 0; r < 4; ++r)
                    h[(size_t)(row0 + i * 16 + r) * D + col0 + jj * 16] =
                        f2h(acc[i][jj][r]);
    }
}

// ==== merged post1: blocks [0,N) s1s2 rows; [N, N+2048) h->hT transpose ====
__global__ __launch_bounds__(256) void post1_kernel(
    const u16* __restrict__ h, const u16* __restrict__ a,
    float* __restrict__ s1, float* __restrict__ s2,
    u16* __restrict__ hT, int N, int D)
{
    __shared__ u16 tile[64][68];
    __shared__ float r1[4], r2[4];
    const int b = blockIdx.x;
    const int t = threadIdx.x;

    if (b < N) {
        const u16* hr = h + (size_t)b * D;
        const int k0 = t * 8;
        float acc1 = 0.f, acc2 = 0.f;
#pragma unroll
        for (int u = 0; u < 8; u += 4) {
            ushort4 hv  = *(const ushort4*)&hr[k0 + u];
            ushort4 a1v = *(const ushort4*)&a[k0 + u];
            ushort4 a2v = *(const ushort4*)&a[D + k0 + u];
            acc1 += h2f(hv.x) * h2f(a1v.x) + h2f(hv.y) * h2f(a1v.y)
                  + h2f(hv.z) * h2f(a1v.z) + h2f(hv.w) * h2f(a1v.w);
            acc2 += h2f(hv.x) * h2f(a2v.x) + h2f(hv.y) * h2f(a2v.y)
                  + h2f(hv.z) * h2f(a2v.z) + h2f(hv.w) * h2f(a2v.w);
        }
        const int lane = t & 63, wv = t >> 6;
#pragma unroll
        for (int o = 32; o > 0; o >>= 1) {
            acc1 += __shfl_down(acc1, o, 64);
            acc2 += __shfl_down(acc2, o, 64);
        }
        if (lane == 0) { r1[wv] = acc1; r2[wv] = acc2; }
        __syncthreads();
        if (t == 0) {
            s1[b] = r1[0] + r1[1] + r1[2] + r1[3];
            s2[b] = r2[0] + r2[1] + r2[2] + r2[3];
        }
    } else {
        const int tt = b - N;
        const int bc = (tt & 31) * 64;
        const int br = (tt >> 5) * 64;
        const int lr = t >> 4;
        const int lc = (t & 15) * 4;
#pragma unroll
        for (int s = 0; s < 4; ++s) {
            const int r = lr + s * 16;
            ushort4 v = *(const ushort4*)&h[(size_t)(br + r) * D + bc + lc];
            tile[r][lc + 0] = v.x; tile[r][lc + 1] = v.y;
            tile[r][lc + 2] = v.z; tile[r][lc + 3] = v.w;
        }
        __syncthreads();
#pragma unroll
        for (int s = 0; s < 4; ++s) {
            const int oc = lr + s * 16;
            ushort4 v;
            v.x = tile[lc + 0][oc]; v.y = tile[lc + 1][oc];
            v.z = tile[lc + 2][oc]; v.w = tile[lc + 3][oc];
            *(ushort4*)&hT[(size_t)(bc + oc) * N + br + lc] = v;
        }
    }
}

// ---- row softmax: P flags in, f16 probs out ----
__global__ __launch_bounds__(256) void softmax_kernel(
    u16* __restrict__ P, const float* __restrict__ s1,
    const float* __restrict__ s2, int N)
{
    const int row = blockIdx.x;
    const int t = threadIdx.x;
    const int lane = t & 63, wv = t >> 6;
    u16* prow = P + (size_t)row * N;
    const float s1v = s1[row];

    float e[16];
#pragma unroll
    for (int it = 0; it < 16; ++it) {
        const int j = it * 256 + t;
        const u16 f = prow[j];
        float ev = s1v + s2[j];
        ev = ev >= 0.f ? ev : 0.1f * ev;
        e[it] = f ? ev : -9.0e15f;
    }
    float m = -3.4e38f;
#pragma unroll
    for (int it = 0; it < 16; ++it) m = fmaxf(m, e[it]);
#pragma unroll
    for (int o = 32; o > 0; o >>= 1) m = fmaxf(m, __shfl_xor(m, o, 64));
    __shared__ float red[8];
    if (lane == 0) red[wv] = m;
    __syncthreads();
    m = fmaxf(fmaxf(red[0], red[1]), fmaxf(red[2], red[3]));

    float sum = 0.f;
#pragma unroll
    for (int it = 0; it < 16; ++it) {
        e[it] = expf(fminf(e[it] - m, 0.0f));
        sum += e[it];
    }
#pragma unroll
    for (int o = 32; o > 0; o >>= 1) sum += __shfl_xor(sum, o, 64);
    if (lane == 0) red[4 + wv] = sum;
    __syncthreads();
    sum = red[4] + red[5] + red[6] + red[7];
    const float inv = 1.f / fmaxf(sum, 1e-30f);
#pragma unroll
    for (int it = 0; it < 16; ++it) {
        const int j = it * 256 + t;
        prow[j] = f2h(e[it] * inv);
    }
}

// ==== out = elu(P @ hT^T): 128x128 tiles, 512 blocks, BK=64, dbuf 64 KB,
// counted-vmcnt pipeline. ====
__global__ __launch_bounds__(256, 2) void gemm_elu(
    const u16* __restrict__ A, int lda,   // P: N x N (f16 probs)
    const u16* __restrict__ B, int ldb,   // hT: D x N
    u16* __restrict__ C, int ldc,         // out: N x D
    int K, const u32* __restrict__ dflag)
{
    __shared__ alignas(16) u16 sm[2][2][128 * 64];   // 64 KB

    const int tid = threadIdx.x;
    const int wave = tid >> 6, lane = tid & 63;
    const int wr = wave >> 1, wc = wave & 1;
    const int q = lane >> 4, mrow = lane & 15;
    const int srow8 = lane >> 3;
    const int gslot = (lane & 7) ^ srow8;

    // XCD swizzle (512 = 8 * 64)
    const int bid = blockIdx.x;
    const int swz = (bid & 7) * 64 + (bid >> 3);
    const int bm = swz >> 4;     // N/128 = 32
    const int bn = swz & 15;     // D/128 = 16

    const u16* Ab = A + (size_t)bm * 128 * lda;
    const u16* Bb = B + (size_t)bn * 128 * ldb;

    f32x4 acc[4][4] = {};

#define STAGE_E(buf, kt)                                                     \
    {                                                                        \
        _Pragma("unroll")                                                    \
        for (int it = 0; it < 4; ++it) {                                     \
            const int c = wave * 4 + it;                                     \
            const int row = c * 8 + srow8;                                   \
            gld_lds16(Ab + (size_t)row * lda + (kt) + gslot * 8,             \
                      &sm[buf][0][c * 512]);                                 \
            gld_lds16(Bb + (size_t)row * ldb + (kt) + gslot * 8,             \
                      &sm[buf][1][c * 512]);                                 \
        }                                                                    \
    }

    const int T = K >> 6;    // 64 steps
    STAGE_E(0, 0);
    for (int t = 0; t < T; ++t) {
        if (t + 1 < T) { STAGE_E((t + 1) & 1, (t + 1) * 64); VMCNT8(); }
        else           { VMCNT0(); }
        SBAR();
        const int buf = t & 1;
        f16x8 a[2][4], b[2][4];
#pragma unroll
        for (int ks = 0; ks < 2; ++ks)
#pragma unroll
            for (int i = 0; i < 4; ++i) {
                const int ra = wr * 64 + i * 16 + mrow;
                const int rb = wc * 64 + i * 16 + mrow;
                const int sa = ((q + 4 * ks) ^ (mrow & 7)) * 8;
                a[ks][i] = *(const f16x8*)&sm[buf][0][ra * 64 + sa];
                b[ks][i] = *(const f16x8*)&sm[buf][1][rb * 64 + sa];
            }
#pragma unroll
        for (int i = 0; i < 4; ++i)
#pragma unroll
            for (int j = 0; j < 4; ++j) {
                acc[i][j] = __builtin_amdgcn_mfma_f32_16x16x32_f16(
                    a[0][i], b[0][j], acc[i][j], 0, 0, 0);
                acc[i][j] = __builtin_amdgcn_mfma_f32_16x16x32_f16(
                    a[1][i], b[1][j], acc[i][j], 0, 0, 0);
            }
        SBAR();
    }
#undef STAGE_E

    const bool isbf = (*dflag != 0);
    float* outF = (float*)C;
    const int row0 = bm * 128 + wr * 64 + q * 4;
    const int col0 = bn * 128 + wc * 64 + mrow;
#pragma unroll
    for (int i = 0; i < 4; ++i)
#pragma unroll
        for (int j = 0; j < 4; ++j)
#pragma unroll
            for (int r = 0; r < 4; ++r) {
                const int row = row0 + i * 16 + r;
                const int col = col0 + j * 16;
                const float v = acc[i][j][r];
                const float o = v > 0.0f ? v : expm1f(v);
                if (isbf) C[(size_t)row * ldc + col] = f2bf(o);
                else      outF[(size_t)row * ldc + col] = o;
            }
}

extern "C" void kernel_launch(void* const* d_in, const int* in_sizes, int n_in,
                              void* d_out, int out_size, void* d_ws, size_t ws_size,
                              hipStream_t stream)
{
    const void* x   = d_in[0];   // 4096 x 2048 (fp32 or bf16 — sniffed)
    const void* adj = d_in[1];   // 4096 x 4096
    const void* W   = d_in[2];   // 2048 x 2048
    const void* a   = d_in[3];   // 4096

    const int N = 4096, D = 2048;

    u16* xhi = (u16*)d_ws;                       // N*D f16
    u16* xlo = xhi + (size_t)N * D;              // N*D f16 (later reused as hT)
    u16* WT  = xlo + (size_t)N * D;              // D*D f16
    u16* h   = WT  + (size_t)D * D;              // N*D f16
    u16* P   = h   + (size_t)N * D;              // N*N (flags, then f16 probs)
    u16* af  = P   + (size_t)N * N;              // 4096 f16
    float* s1 = (float*)(af + 4096);
    float* s2 = s1 + N;
    u32* flag = (u32*)(s2 + N);

    // 0. dtype sniff
    sniff_kernel<<<1, 256, 0, stream>>>((const u16*)x, flag);
    // 1. merged converts (split + WT + a)
    prep_kernel<<<dim3(2049), 256, 0, stream>>>(x, W, a, xhi, xlo, WT, af,
                                                flag, N, D);
    // 2. fused: triangle mask (528) + h = x@W (512), BK=64 counted-vmcnt dbuf
    fused_mask_h<<<dim3(1040), 256, 0, stream>>>(
        xhi, xlo, D, P, N, adj, WT, D, h, flag);
    // 3. merged s1s2 (4096) + h->hT transpose (2048) (hT into xlo)
    post1_kernel<<<dim3(N + 2048), 256, 0, stream>>>(h, af, s1, s2, xlo, N, D);
    // 4. softmax rows -> P probs (f16)
    softmax_kernel<<<dim3(N), 256, 0, stream>>>(P, s1, s2, N);
    // 5. out = elu(P @ h), BK=64 counted-vmcnt dbuf
    gemm_elu<<<dim3(512), 256, 0, stream>>>(
        P, N, xlo, N, (u16*)d_out, D, N, flag);
}

// Round 6
// 453.248 us; speedup vs baseline: 1.2162x; 1.2162x over previous
//
#include <hip/hip_runtime.h>
#include <hip/hip_bf16.h>
#include <cmath>

typedef unsigned short u16;
typedef unsigned char u8;
typedef unsigned int u32;
typedef __attribute__((ext_vector_type(8))) _Float16 f16x8;
typedef __attribute__((ext_vector_type(4))) float f32x4;

__device__ __forceinline__ float bf2f(u16 v) {
    union { u32 u; float f; } c; c.u = (u32)v << 16; return c.f;
}
__device__ __forceinline__ u16 f2bf(float f) {
    union { float f; u32 u; } c; c.f = f;
    u32 u = c.u;
    u += 0x7FFF + ((u >> 16) & 1);
    return (u16)(u >> 16);
}
__device__ __forceinline__ u16 f2h(float f) {
    _Float16 h = (_Float16)f; u16 r; __builtin_memcpy(&r, &h, 2); return r;
}
__device__ __forceinline__ float h2f(u16 b) {
    _Float16 h; __builtin_memcpy(&h, &b, 2); return (float)h;
}

// async global->LDS DMA, 16B/lane; LDS dest = wave-uniform base + lane*16
__device__ __forceinline__ void gld_lds16(const void* g, void* l) {
    __builtin_amdgcn_global_load_lds(
        (const __attribute__((address_space(1))) void*)g,
        (__attribute__((address_space(3))) void*)l, 16, 0, 0);
}

// catalog 2-phase primitives: drain at END of step, ONE barrier per step
#define VMCNT0()  asm volatile("s_waitcnt vmcnt(0)" ::: "memory")
#define SBAR()    asm volatile("s_barrier" ::: "memory")

// ---- dtype sniff: flag=1 if raw u16 stream looks like bf16, 0 if fp32 ----
__global__ __launch_bounds__(256) void sniff_kernel(const u16* __restrict__ x,
                                                    u32* __restrict__ flag) {
    const int t = threadIdx.x;
    int local = 0;
    for (int i = t; i < 4096; i += 256) {
        const int e = (x[i] >> 7) & 0xFF;
        if (e >= 110 && e <= 137) local++;
    }
#pragma unroll
    for (int o = 32; o > 0; o >>= 1) local += __shfl_down(local, o, 64);
    __shared__ int s[4];
    if ((t & 63) == 0) s[t >> 6] = local;
    __syncthreads();
    if (t == 0) {
        const int tot = s[0] + s[1] + s[2] + s[3];
        *flag = (tot >= 3200) ? 1u : 0u;
    }
}

// ==== merged prep: blocks [0,1024) conv_split, [1024,2048) conv_wt,
// [2048] conv_a. ====
__global__ __launch_bounds__(256) void prep_kernel(
    const void* __restrict__ xin, const void* __restrict__ Win,
    const void* __restrict__ ain,
    u16* __restrict__ xhi, u16* __restrict__ xlo,
    u16* __restrict__ WT, u16* __restrict__ aout,
    const u32* __restrict__ flag, int N, int D)
{
    __shared__ u16 tile[64][68];
    const bool isbf = (*flag != 0);
    const int b = blockIdx.x;
    const int t = threadIdx.x;

    if (b < 1024) {
        const long base = (long)b * 8192;
#pragma unroll
        for (int it = 0; it < 8; ++it) {
            const long i = base + (long)(it * 256 + t) * 4;
            float v[4];
            if (isbf) {
                ushort4 u = *(const ushort4*)((const u16*)xin + i);
                v[0] = bf2f(u.x); v[1] = bf2f(u.y); v[2] = bf2f(u.z); v[3] = bf2f(u.w);
            } else {
                float4 f = *(const float4*)((const float*)xin + i);
                v[0] = f.x; v[1] = f.y; v[2] = f.z; v[3] = f.w;
            }
            ushort4 hi, lo;
            u16* hp = &hi.x; u16* lp = &lo.x;
#pragma unroll
            for (int k = 0; k < 4; ++k) {
                _Float16 h = (_Float16)v[k];
                u16 hb; __builtin_memcpy(&hb, &h, 2);
                hp[k] = hb;
                lp[k] = f2h(v[k] - (float)h);
            }
            *(ushort4*)(xhi + i) = hi;
            *(ushort4*)(xlo + i) = lo;
        }
    } else if (b < 2048) {
        const int tt = b - 1024;
        const int bc = (tt & 31) * 64;
        const int br = (tt >> 5) * 64;
        const int lr = t >> 4;
        const int lc = (t & 15) * 4;
#pragma unroll
        for (int s = 0; s < 4; ++s) {
            const int r = lr + s * 16;
            float v[4];
            if (isbf) {
                ushort4 u = *(const ushort4*)((const u16*)Win + (size_t)(br + r) * D + bc + lc);
                v[0] = bf2f(u.x); v[1] = bf2f(u.y); v[2] = bf2f(u.z); v[3] = bf2f(u.w);
            } else {
                float4 f = *(const float4*)((const float*)Win + (size_t)(br + r) * D + bc + lc);
                v[0] = f.x; v[1] = f.y; v[2] = f.z; v[3] = f.w;
            }
            tile[r][lc + 0] = f2h(v[0]); tile[r][lc + 1] = f2h(v[1]);
            tile[r][lc + 2] = f2h(v[2]); tile[r][lc + 3] = f2h(v[3]);
        }
        __syncthreads();
#pragma unroll
        for (int s = 0; s < 4; ++s) {
            const int oc = lr + s * 16;
            ushort4 v;
            v.x = tile[lc + 0][oc]; v.y = tile[lc + 1][oc];
            v.z = tile[lc + 2][oc]; v.w = tile[lc + 3][oc];
            *(ushort4*)&WT[(size_t)(bc + oc) * D + br + lc] = v;
        }
    } else {
        for (int i = t; i < 2 * D; i += 256) {
            float v = isbf ? bf2f(((const u16*)ain)[i]) : ((const float*)ain)[i];
            aout[i] = f2h(v);
        }
    }
}

// ==== FUSED: triangle mask (0..527) + h=x@W (528..1039).
// 128x128 tiles, 4 waves, BK=32, DOUBLE-buffered 32 KB LDS, catalog 2-phase:
//   STAGE(next buf) -> ds_read(cur)+MFMA(cur) -> vmcnt(0) -> ONE s_barrier.
// Stage loads fly under the ds_read+MFMA phase; drain at end is cheap.
// 32 KB keeps the R4 occupancy regime (~5 resident blocks LDS-wise).
#define NMASK 528
#define MAXFIX 1024
#define MTAU 0.125f
__global__ __launch_bounds__(256, 2) void fused_mask_h(
    const u16* __restrict__ Xhi, const u16* __restrict__ Xlo, int ldx,
    u16* __restrict__ P, int N,
    const void* __restrict__ adj,
    const u16* __restrict__ WT, int D,
    u16* __restrict__ h,
    const u32* __restrict__ dflag)
{
    __shared__ alignas(16) u16 sm[2][2][128 * 32];   // [buf][A/B], 32 KB

    const int tid = threadIdx.x;
    const int wave = tid >> 6, lane = tid & 63;
    const int wr = wave >> 1, wc = wave & 1;          // 2x2 waves over 128x128
    const int q = lane >> 4, mrow = lane & 15;        // mfma frag coords
    const int srow = lane >> 2, slot = lane & 3;      // staging: 16 rows x 4 chunks

    const int bid = blockIdx.x;
    const bool isbf = (*dflag != 0);

    if (bid < NMASK) {
        // ---- mask: triangle block (bm >= bn) of adj*(x@x^T) > 0 ----
        const int idx = bid;
        int bm = (int)((__builtin_sqrtf(8.0f * idx + 1.0f) - 1.0f) * 0.5f);
        while ((bm + 1) * (bm + 2) / 2 <= idx) ++bm;
        while (bm * (bm + 1) / 2 > idx) --bm;
        const int bn = idx - bm * (bm + 1) / 2;   // bn <= bm

        const u16* Ab = Xhi + (size_t)bm * 128 * ldx;
        const u16* Bb = Xhi + (size_t)bn * 128 * ldx;

        f32x4 acc[4][4] = {};

#define STAGE_M(buf, kt)                                                     \
        {                                                                    \
            _Pragma("unroll")                                                \
            for (int it = 0; it < 2; ++it) {                                 \
                const int c = wave * 2 + it;                                 \
                const int row = c * 16 + srow;                               \
                const size_t go = (size_t)row * ldx + (kt) + slot * 8;       \
                gld_lds16(Ab + go, &sm[buf][0][c * 512]);                    \
                gld_lds16(Bb + go, &sm[buf][1][c * 512]);                    \
            }                                                                \
        }

        const int T = ldx >> 5;                 // 64 K-steps of BK=32
        STAGE_M(0, 0);
        VMCNT0(); SBAR();
        for (int t = 0; t < T; ++t) {
            const int buf = t & 1;
            if (t + 1 < T) STAGE_M(buf ^ 1, (t + 1) * 32);
            f16x8 a[4], b[4];
#pragma unroll
            for (int i = 0; i < 4; ++i) {
                a[i] = *(const f16x8*)&sm[buf][0][(wr * 64 + i * 16 + mrow) * 32 + q * 8];
                b[i] = *(const f16x8*)&sm[buf][1][(wc * 64 + i * 16 + mrow) * 32 + q * 8];
            }
#pragma unroll
            for (int i = 0; i < 4; ++i)
#pragma unroll
                for (int j = 0; j < 4; ++j)
                    acc[i][j] = __builtin_amdgcn_mfma_f32_16x16x32_f16(
                        a[i], b[j], acc[i][j], 0, 0, 0);
            VMCNT0(); SBAR();                   // next buf landed; cur reads done
        }
#undef STAGE_M

        const u16* adjB = (const u16*)adj;
        const float* adjF = (const float*)adj;
        const float tau = isbf ? -1.0f : MTAU;   // bf16->f16 exact: no fixup

        // ---- epilogue: sign tile + borderline fixup + masked P writes ----
        u8* sgn = (u8*)sm;                        // 128 x 132 = 16896 B
        u32* list = (u32*)((u8*)sm + 24576);      // MAXFIX u32
        int* cntp = (int*)((u8*)sm + 28672);

        if (tid == 0) *cntp = 0;
#pragma unroll
        for (int i = 0; i < 4; ++i)
#pragma unroll
            for (int j = 0; j < 4; ++j)
#pragma unroll
                for (int r = 0; r < 4; ++r) {
                    const int rl = wr * 64 + i * 16 + q * 4 + r;
                    const int cl = wc * 64 + j * 16 + mrow;
                    const float v = acc[i][j][r];
                    sgn[rl * 132 + cl] = v > 0.f ? (u8)1
                                       : (v < 0.f ? (u8)2 : (u8)0);
                }
        __syncthreads();

#pragma unroll
        for (int i = 0; i < 4; ++i)
#pragma unroll
            for (int j = 0; j < 4; ++j)
#pragma unroll
                for (int r = 0; r < 4; ++r)
                    if (__builtin_fabsf(acc[i][j][r]) < tau) {
                        const int rl = wr * 64 + i * 16 + q * 4 + r;
                        const int cl = wc * 64 + j * 16 + mrow;
                        const int ix = atomicAdd(cntp, 1);
                        if (ix < MAXFIX) list[ix] = (u32)((rl << 8) | cl);
                    }
        __syncthreads();

        const int nfix = (*cntp < MAXFIX) ? *cntp : MAXFIX;
        for (int e = wave; e < nfix; e += 4) {
            const u32 pk = list[e];
            const int rl = (int)(pk >> 8), cl = (int)(pk & 255u);
            const u16* arh = Xhi + (size_t)(bm * 128 + rl) * ldx;
            const u16* arl = Xlo + (size_t)(bm * 128 + rl) * ldx;
            const u16* brh = Xhi + (size_t)(bn * 128 + cl) * ldx;
            const u16* brl = Xlo + (size_t)(bn * 128 + cl) * ldx;
            float ssum = 0.f;
#pragma unroll
            for (int kk = 0; kk < 4; ++kk) {
                const int k = kk * 512 + lane * 8;
                const f16x8 vah = *(const f16x8*)&arh[k];
                const f16x8 val2 = *(const f16x8*)&arl[k];
                const f16x8 vbh = *(const f16x8*)&brh[k];
                const f16x8 vbl = *(const f16x8*)&brl[k];
#pragma unroll
                for (int u = 0; u < 8; ++u)
                    ssum += ((float)vah[u] + (float)val2[u]) *
                            ((float)vbh[u] + (float)vbl[u]);
            }
#pragma unroll
            for (int o = 32; o > 0; o >>= 1) ssum += __shfl_xor(ssum, o, 64);
            if (lane == 0)
                sgn[rl * 132 + cl] = ssum > 0.f ? (u8)1
                                   : (ssum < 0.f ? (u8)2 : (u8)0);
        }
        __syncthreads();

        // normal orientation: coalesced, via sign tile
        {
            const int c = tid & 127;
            const int r0 = tid >> 7;
#pragma unroll 4
            for (int s = 0; s < 64; ++s) {
                const int rr = r0 + 2 * s;
                const u8 s3 = sgn[rr * 132 + c];
                const size_t aidx = (size_t)(bm * 128 + rr) * N + bn * 128 + c;
                const float av = isbf ? bf2f(adjB[aidx]) : adjF[aidx];
                const bool f = (s3 == 1) ? (av > 0.f)
                             : (s3 == 2) ? (av < 0.f) : false;
                P[aidx] = f ? (u16)1 : (u16)0;
            }
        }

        if (bm != bn) {
            // transposed orientation (stride-132 sign reads, conflict-free)
            const int bl_ = tid & 63;
            const int a0 = tid >> 6;
#pragma unroll 4
            for (int s = 0; s < 32; ++s) {
                const int a = a0 + 4 * s;
#pragma unroll
                for (int hb = 0; hb < 2; ++hb) {
                    const int b = bl_ + 64 * hb;
                    const u8 s3 = sgn[b * 132 + a];
                    const size_t aidx = (size_t)(bn * 128 + a) * N + bm * 128 + b;
                    const float av = isbf ? bf2f(adjB[aidx]) : adjF[aidx];
                    const bool f = (s3 == 1) ? (av > 0.f)
                                 : (s3 == 2) ? (av < 0.f) : false;
                    P[aidx] = f ? (u16)1 : (u16)0;
                }
            }
        }
    } else {
        // ---- h = x @ W (NT against WT) ----
        const int j = bid - NMASK;
        const int bn = j & 15;    // D/128 = 16
        const int bm = j >> 4;    // N/128 = 32

        const u16* Ab = Xhi + (size_t)bm * 128 * ldx;
        const u16* Bb = WT + (size_t)bn * 128 * D;

        f32x4 acc[4][4] = {};

#define STAGE_H(buf, kt)                                                     \
        {                                                                    \
            _Pragma("unroll")                                                \
            for (int it = 0; it < 2; ++it) {                                 \
                const int c = wave * 2 + it;                                 \
                const int row = c * 16 + srow;                               \
                gld_lds16(Ab + (size_t)row * ldx + (kt) + slot * 8,          \
                          &sm[buf][0][c * 512]);                             \
                gld_lds16(Bb + (size_t)row * D + (kt) + slot * 8,            \
                          &sm[buf][1][c * 512]);                             \
            }                                                                \
        }

        const int T = D >> 5;
        STAGE_H(0, 0);
        VMCNT0(); SBAR();
        for (int t = 0; t < T; ++t) {
            const int buf = t & 1;
            if (t + 1 < T) STAGE_H(buf ^ 1, (t + 1) * 32);
            f16x8 a[4], b[4];
#pragma unroll
            for (int i = 0; i < 4; ++i) {
                a[i] = *(const f16x8*)&sm[buf][0][(wr * 64 + i * 16 + mrow) * 32 + q * 8];
                b[i] = *(const f16x8*)&sm[buf][1][(wc * 64 + i * 16 + mrow) * 32 + q * 8];
            }
#pragma unroll
            for (int i = 0; i < 4; ++i)
#pragma unroll
                for (int jj = 0; jj < 4; ++jj)
                    acc[i][jj] = __builtin_amdgcn_mfma_f32_16x16x32_f16(
                        a[i], b[jj], acc[i][jj], 0, 0, 0);
            VMCNT0(); SBAR();
        }
#undef STAGE_H

        const int row0 = bm * 128 + wr * 64 + q * 4;
        const int col0 = bn * 128 + wc * 64 + mrow;
#pragma unroll
        for (int i = 0; i < 4; ++i)
#pragma unroll
            for (int jj = 0; jj < 4; ++jj)
#pragma unroll
                for (int r = 0; r < 4; ++r)
                    h[(size_t)(row0 + i * 16 + r) * D + col0 + jj * 16] =
                        f2h(acc[i][jj][r]);
    }
}

// ==== merged post1: blocks [0,N) s1s2 rows; [N, N+2048) h->hT transpose ====
__global__ __launch_bounds__(256) void post1_kernel(
    const u16* __restrict__ h, const u16* __restrict__ a,
    float* __restrict__ s1, float* __restrict__ s2,
    u16* __restrict__ hT, int N, int D)
{
    __shared__ u16 tile[64][68];
    __shared__ float r1[4], r2[4];
    const int b = blockIdx.x;
    const int t = threadIdx.x;

    if (b < N) {
        const u16* hr = h + (size_t)b * D;
        const int k0 = t * 8;
        float acc1 = 0.f, acc2 = 0.f;
#pragma unroll
        for (int u = 0; u < 8; u += 4) {
            ushort4 hv  = *(const ushort4*)&hr[k0 + u];
            ushort4 a1v = *(const ushort4*)&a[k0 + u];
            ushort4 a2v = *(const ushort4*)&a[D + k0 + u];
            acc1 += h2f(hv.x) * h2f(a1v.x) + h2f(hv.y) * h2f(a1v.y)
                  + h2f(hv.z) * h2f(a1v.z) + h2f(hv.w) * h2f(a1v.w);
            acc2 += h2f(hv.x) * h2f(a2v.x) + h2f(hv.y) * h2f(a2v.y)
                  + h2f(hv.z) * h2f(a2v.z) + h2f(hv.w) * h2f(a2v.w);
        }
        const int lane = t & 63, wv = t >> 6;
#pragma unroll
        for (int o = 32; o > 0; o >>= 1) {
            acc1 += __shfl_down(acc1, o, 64);
            acc2 += __shfl_down(acc2, o, 64);
        }
        if (lane == 0) { r1[wv] = acc1; r2[wv] = acc2; }
        __syncthreads();
        if (t == 0) {
            s1[b] = r1[0] + r1[1] + r1[2] + r1[3];
            s2[b] = r2[0] + r2[1] + r2[2] + r2[3];
        }
    } else {
        const int tt = b - N;
        const int bc = (tt & 31) * 64;
        const int br = (tt >> 5) * 64;
        const int lr = t >> 4;
        const int lc = (t & 15) * 4;
#pragma unroll
        for (int s = 0; s < 4; ++s) {
            const int r = lr + s * 16;
            ushort4 v = *(const ushort4*)&h[(size_t)(br + r) * D + bc + lc];
            tile[r][lc + 0] = v.x; tile[r][lc + 1] = v.y;
            tile[r][lc + 2] = v.z; tile[r][lc + 3] = v.w;
        }
        __syncthreads();
#pragma unroll
        for (int s = 0; s < 4; ++s) {
            const int oc = lr + s * 16;
            ushort4 v;
            v.x = tile[lc + 0][oc]; v.y = tile[lc + 1][oc];
            v.z = tile[lc + 2][oc]; v.w = tile[lc + 3][oc];
            *(ushort4*)&hT[(size_t)(bc + oc) * N + br + lc] = v;
        }
    }
}

// ---- row softmax: P flags in, f16 probs out ----
__global__ __launch_bounds__(256) void softmax_kernel(
    u16* __restrict__ P, const float* __restrict__ s1,
    const float* __restrict__ s2, int N)
{
    const int row = blockIdx.x;
    const int t = threadIdx.x;
    const int lane = t & 63, wv = t >> 6;
    u16* prow = P + (size_t)row * N;
    const float s1v = s1[row];

    float e[16];
#pragma unroll
    for (int it = 0; it < 16; ++it) {
        const int j = it * 256 + t;
        const u16 f = prow[j];
        float ev = s1v + s2[j];
        ev = ev >= 0.f ? ev : 0.1f * ev;
        e[it] = f ? ev : -9.0e15f;
    }
    float m = -3.4e38f;
#pragma unroll
    for (int it = 0; it < 16; ++it) m = fmaxf(m, e[it]);
#pragma unroll
    for (int o = 32; o > 0; o >>= 1) m = fmaxf(m, __shfl_xor(m, o, 64));
    __shared__ float red[8];
    if (lane == 0) red[wv] = m;
    __syncthreads();
    m = fmaxf(fmaxf(red[0], red[1]), fmaxf(red[2], red[3]));

    float sum = 0.f;
#pragma unroll
    for (int it = 0; it < 16; ++it) {
        e[it] = expf(fminf(e[it] - m, 0.0f));
        sum += e[it];
    }
#pragma unroll
    for (int o = 32; o > 0; o >>= 1) sum += __shfl_xor(sum, o, 64);
    if (lane == 0) red[4 + wv] = sum;
    __syncthreads();
    sum = red[4] + red[5] + red[6] + red[7];
    const float inv = 1.f / fmaxf(sum, 1e-30f);
#pragma unroll
    for (int it = 0; it < 16; ++it) {
        const int j = it * 256 + t;
        prow[j] = f2h(e[it] * inv);
    }
}

// ==== out = elu(P @ hT^T): 128x128 tiles, grid (16,32), BK=32 dbuf 32 KB,
// catalog 2-phase order. ====
__global__ __launch_bounds__(256, 2) void gemm_elu(
    const u16* __restrict__ A, int lda,   // P: N x N (f16 probs)
    const u16* __restrict__ B, int ldb,   // hT: D x N
    u16* __restrict__ C, int ldc,         // out: N x D
    int K, const u32* __restrict__ dflag)
{
    __shared__ alignas(16) u16 sm[2][2][128 * 32];   // 32 KB

    const int tid = threadIdx.x;
    const int wave = tid >> 6, lane = tid & 63;
    const int wr = wave >> 1, wc = wave & 1;
    const int q = lane >> 4, mrow = lane & 15;
    const int srow = lane >> 2, slot = lane & 3;

    const int bm = blockIdx.y;   // N/128 = 32
    const int bn = blockIdx.x;   // D/128 = 16

    const u16* Ab = A + (size_t)bm * 128 * lda;
    const u16* Bb = B + (size_t)bn * 128 * ldb;

    f32x4 acc[4][4] = {};

#define STAGE_E(buf, kt)                                                     \
    {                                                                        \
        _Pragma("unroll")                                                    \
        for (int it = 0; it < 2; ++it) {                                     \
            const int c = wave * 2 + it;                                     \
            const int row = c * 16 + srow;                                   \
            gld_lds16(Ab + (size_t)row * lda + (kt) + slot * 8,              \
                      &sm[buf][0][c * 512]);                                 \
            gld_lds16(Bb + (size_t)row * ldb + (kt) + slot * 8,              \
                      &sm[buf][1][c * 512]);                                 \
        }                                                                    \
    }

    const int T = K >> 5;    // 128 steps
    STAGE_E(0, 0);
    VMCNT0(); SBAR();
    for (int t = 0; t < T; ++t) {
        const int buf = t & 1;
        if (t + 1 < T) STAGE_E(buf ^ 1, (t + 1) * 32);
        f16x8 a[4], b[4];
#pragma unroll
        for (int i = 0; i < 4; ++i) {
            a[i] = *(const f16x8*)&sm[buf][0][(wr * 64 + i * 16 + mrow) * 32 + q * 8];
            b[i] = *(const f16x8*)&sm[buf][1][(wc * 64 + i * 16 + mrow) * 32 + q * 8];
        }
#pragma unroll
        for (int i = 0; i < 4; ++i)
#pragma unroll
            for (int j = 0; j < 4; ++j)
                acc[i][j] = __builtin_amdgcn_mfma_f32_16x16x32_f16(
                    a[i], b[j], acc[i][j], 0, 0, 0);
        VMCNT0(); SBAR();
    }
#undef STAGE_E

    const bool isbf = (*dflag != 0);
    float* outF = (float*)C;
    const int row0 = bm * 128 + wr * 64 + q * 4;
    const int col0 = bn * 128 + wc * 64 + mrow;
#pragma unroll
    for (int i = 0; i < 4; ++i)
#pragma unroll
        for (int j = 0; j < 4; ++j)
#pragma unroll
            for (int r = 0; r < 4; ++r) {
                const int row = row0 + i * 16 + r;
                const int col = col0 + j * 16;
                const float v = acc[i][j][r];
                const float o = v > 0.0f ? v : expm1f(v);
                if (isbf) C[(size_t)row * ldc + col] = f2bf(o);
                else      outF[(size_t)row * ldc + col] = o;
            }
}

extern "C" void kernel_launch(void* const* d_in, const int* in_sizes, int n_in,
                              void* d_out, int out_size, void* d_ws, size_t ws_size,
                              hipStream_t stream)
{
    const void* x   = d_in[0];   // 4096 x 2048 (fp32 or bf16 — sniffed)
    const void* adj = d_in[1];   // 4096 x 4096
    const void* W   = d_in[2];   // 2048 x 2048
    const void* a   = d_in[3];   // 4096

    const int N = 4096, D = 2048;

    u16* xhi = (u16*)d_ws;                       // N*D f16
    u16* xlo = xhi + (size_t)N * D;              // N*D f16 (later reused as hT)
    u16* WT  = xlo + (size_t)N * D;              // D*D f16
    u16* h   = WT  + (size_t)D * D;              // N*D f16
    u16* P   = h   + (size_t)N * D;              // N*N (flags, then f16 probs)
    u16* af  = P   + (size_t)N * N;              // 4096 f16
    float* s1 = (float*)(af + 4096);
    float* s2 = s1 + N;
    u32* flag = (u32*)(s2 + N);

    // 0. dtype sniff
    sniff_kernel<<<1, 256, 0, stream>>>((const u16*)x, flag);
    // 1. merged converts (split + WT + a)
    prep_kernel<<<dim3(2049), 256, 0, stream>>>(x, W, a, xhi, xlo, WT, af,
                                                flag, N, D);
    // 2. fused: triangle mask (528) + h = x@W (512), BK=32 2-phase dbuf
    fused_mask_h<<<dim3(1040), 256, 0, stream>>>(
        xhi, xlo, D, P, N, adj, WT, D, h, flag);
    // 3. merged s1s2 (4096) + h->hT transpose (2048) (hT into xlo)
    post1_kernel<<<dim3(N + 2048), 256, 0, stream>>>(h, af, s1, s2, xlo, N, D);
    // 4. softmax rows -> P probs (f16)
    softmax_kernel<<<dim3(N), 256, 0, stream>>>(P, s1, s2, N);
    // 5. out = elu(P @ h), BK=32 2-phase dbuf
    gemm_elu<<<dim3(D / 128, N / 128), 256, 0, stream>>>(
        P, N, xlo, N, (u16*)d_out, D, N, flag);
}

// Round 7
// 392.871 us; speedup vs baseline: 1.4031x; 1.1537x over previous
//
#include <hip/hip_runtime.h>
#include <hip/hip_bf16.h>
#include <cmath>

typedef unsigned short u16;
typedef unsigned char u8;
typedef unsigned int u32;
typedef __attribute__((ext_vector_type(8))) _Float16 f16x8;
typedef __attribute__((ext_vector_type(4))) float f32x4;

__device__ __forceinline__ float bf2f(u16 v) {
    union { u32 u; float f; } c; c.u = (u32)v << 16; return c.f;
}
__device__ __forceinline__ u16 f2bf(float f) {
    union { float f; u32 u; } c; c.f = f;
    u32 u = c.u;
    u += 0x7FFF + ((u >> 16) & 1);
    return (u16)(u >> 16);
}
__device__ __forceinline__ u16 f2h(float f) {
    _Float16 h = (_Float16)f; u16 r; __builtin_memcpy(&r, &h, 2); return r;
}
__device__ __forceinline__ float h2f(u16 b) {
    _Float16 h; __builtin_memcpy(&h, &b, 2); return (float)h;
}

// async global->LDS DMA, 16B/lane; LDS dest = wave-uniform base + lane*16
__device__ __forceinline__ void gld_lds16(const void* g, void* l) {
    __builtin_amdgcn_global_load_lds(
        (const __attribute__((address_space(1))) void*)g,
        (__attribute__((address_space(3))) void*)l, 16, 0, 0);
}

// ---- dtype sniff: flag=1 if raw u16 stream looks like bf16, 0 if fp32 ----
__global__ __launch_bounds__(256) void sniff_kernel(const u16* __restrict__ x,
                                                    u32* __restrict__ flag) {
    const int t = threadIdx.x;
    int local = 0;
    for (int i = t; i < 4096; i += 256) {
        const int e = (x[i] >> 7) & 0xFF;
        if (e >= 110 && e <= 137) local++;
    }
#pragma unroll
    for (int o = 32; o > 0; o >>= 1) local += __shfl_down(local, o, 64);
    __shared__ int s[4];
    if ((t & 63) == 0) s[t >> 6] = local;
    __syncthreads();
    if (t == 0) {
        const int tot = s[0] + s[1] + s[2] + s[3];
        *flag = (tot >= 3200) ? 1u : 0u;
    }
}

// ==== merged prep: [0,1024) conv_split, [1024,2048) conv_wt, [2048] conv_a,
// [2049,3073) adj -> 2-bit sign map (0=zero, 1=pos, 2=neg; 4 entries/byte).
__global__ __launch_bounds__(256) void prep_kernel(
    const void* __restrict__ xin, const void* __restrict__ Win,
    const void* __restrict__ ain, const void* __restrict__ adjin,
    u16* __restrict__ xhi, u16* __restrict__ xlo,
    u16* __restrict__ WT, u16* __restrict__ aout,
    u8* __restrict__ asgn,
    const u32* __restrict__ flag, int N, int D)
{
    __shared__ u16 tile[64][68];
    const bool isbf = (*flag != 0);
    const int b = blockIdx.x;
    const int t = threadIdx.x;

    if (b < 1024) {
        const long base = (long)b * 8192;
#pragma unroll
        for (int it = 0; it < 8; ++it) {
            const long i = base + (long)(it * 256 + t) * 4;
            float v[4];
            if (isbf) {
                ushort4 u = *(const ushort4*)((const u16*)xin + i);
                v[0] = bf2f(u.x); v[1] = bf2f(u.y); v[2] = bf2f(u.z); v[3] = bf2f(u.w);
            } else {
                float4 f = *(const float4*)((const float*)xin + i);
                v[0] = f.x; v[1] = f.y; v[2] = f.z; v[3] = f.w;
            }
            ushort4 hi, lo;
            u16* hp = &hi.x; u16* lp = &lo.x;
#pragma unroll
            for (int k = 0; k < 4; ++k) {
                _Float16 h = (_Float16)v[k];
                u16 hb; __builtin_memcpy(&hb, &h, 2);
                hp[k] = hb;
                lp[k] = f2h(v[k] - (float)h);
            }
            *(ushort4*)(xhi + i) = hi;
            *(ushort4*)(xlo + i) = lo;
        }
    } else if (b < 2048) {
        const int tt = b - 1024;
        const int bc = (tt & 31) * 64;
        const int br = (tt >> 5) * 64;
        const int lr = t >> 4;
        const int lc = (t & 15) * 4;
#pragma unroll
        for (int s = 0; s < 4; ++s) {
            const int r = lr + s * 16;
            float v[4];
            if (isbf) {
                ushort4 u = *(const ushort4*)((const u16*)Win + (size_t)(br + r) * D + bc + lc);
                v[0] = bf2f(u.x); v[1] = bf2f(u.y); v[2] = bf2f(u.z); v[3] = bf2f(u.w);
            } else {
                float4 f = *(const float4*)((const float*)Win + (size_t)(br + r) * D + bc + lc);
                v[0] = f.x; v[1] = f.y; v[2] = f.z; v[3] = f.w;
            }
            tile[r][lc + 0] = f2h(v[0]); tile[r][lc + 1] = f2h(v[1]);
            tile[r][lc + 2] = f2h(v[2]); tile[r][lc + 3] = f2h(v[3]);
        }
        __syncthreads();
#pragma unroll
        for (int s = 0; s < 4; ++s) {
            const int oc = lr + s * 16;
            ushort4 v;
            v.x = tile[lc + 0][oc]; v.y = tile[lc + 1][oc];
            v.z = tile[lc + 2][oc]; v.w = tile[lc + 3][oc];
            *(ushort4*)&WT[(size_t)(bc + oc) * D + br + lc] = v;
        }
    } else if (b == 2048) {
        for (int i = t; i < 2 * D; i += 256) {
            float v = isbf ? bf2f(((const u16*)ain)[i]) : ((const float*)ain)[i];
            aout[i] = f2h(v);
        }
    } else {
        // ---- adj sign map: 16384 entries per block, fully coalesced ----
        const long base = (long)(b - 2049) * 16384;
#pragma unroll
        for (int it = 0; it < 4; ++it) {
            const long e0 = base + (long)(it * 256 + t) * 16;
            u8 bytes[4];
            if (isbf) {
                const u16* ap = (const u16*)adjin + e0;
#pragma unroll
                for (int j = 0; j < 4; ++j) {
                    ushort4 v = *(const ushort4*)(ap + j * 4);
                    const u16 vv[4] = {v.x, v.y, v.z, v.w};
                    u8 bb = 0;
#pragma unroll
                    for (int k = 0; k < 4; ++k) {
                        const u16 m = (u16)(vv[k] & 0x7FFF);
                        const u8 c = (m == 0) ? (u8)0
                                   : ((vv[k] >> 15) ? (u8)2 : (u8)1);
                        bb |= (u8)(c << (2 * k));
                    }
                    bytes[j] = bb;
                }
            } else {
                const u32* ap = (const u32*)adjin + e0;
#pragma unroll
                for (int j = 0; j < 4; ++j) {
                    uint4 v = *(const uint4*)(ap + j * 4);
                    const u32 vv[4] = {v.x, v.y, v.z, v.w};
                    u8 bb = 0;
#pragma unroll
                    for (int k = 0; k < 4; ++k) {
                        const u32 m = vv[k] & 0x7FFFFFFFu;
                        const u8 c = (m == 0) ? (u8)0
                                   : ((vv[k] >> 31) ? (u8)2 : (u8)1);
                        bb |= (u8)(c << (2 * k));
                    }
                    bytes[j] = bb;
                }
            }
            uchar4 ov;
            ov.x = bytes[0]; ov.y = bytes[1]; ov.z = bytes[2]; ov.w = bytes[3];
            *(uchar4*)(asgn + (e0 >> 2)) = ov;
        }
    }
}

// ==== FUSED: triangle mask (0..527) + h=x@W (528..1039).
// K-loop: byte-exact R4 (BK=64, single-buffered 32 KB, conflict-free swizzle).
// Epilogue: adj replaced by the 2-bit sign map (no HBM adj reads), vectorized
// ushort4 P writes, aligned u32 sign-tile reads.
#define NMASK 528
#define MAXFIX 1024
#define MTAU 0.125f
__global__ __launch_bounds__(256, 2) void fused_mask_h(
    const u16* __restrict__ Xhi, const u16* __restrict__ Xlo, int ldx,
    u16* __restrict__ P, int N,
    const u8* __restrict__ asgn,
    const u16* __restrict__ WT, int D,
    u16* __restrict__ h,
    const u32* __restrict__ dflag)
{
    __shared__ alignas(16) u16 sm[2][128 * 64];   // [A/B], 32 KB total

    const int tid = threadIdx.x;
    const int wave = tid >> 6, lane = tid & 63;
    const int wr = wave >> 1, wc = wave & 1;          // 2x2 waves over 128x128
    const int q = lane >> 4, mrow = lane & 15;        // mfma frag coords
    const int srow8 = lane >> 3;                      // staging row in 8-row chunk
    const int gslot = (lane & 7) ^ srow8;             // pre-swizzled global slot

    const int bid = blockIdx.x;

    if (bid < NMASK) {
        // ---- mask: triangle block (bm >= bn) of adj*(x@x^T) > 0 ----
        const int idx = bid;
        int bm = (int)((__builtin_sqrtf(8.0f * idx + 1.0f) - 1.0f) * 0.5f);
        while ((bm + 1) * (bm + 2) / 2 <= idx) ++bm;
        while (bm * (bm + 1) / 2 > idx) --bm;
        const int bn = idx - bm * (bm + 1) / 2;   // bn <= bm

        const u16* Ab = Xhi + (size_t)bm * 128 * ldx;
        const u16* Bb = Xhi + (size_t)bn * 128 * ldx;

        f32x4 acc[4][4] = {};

        const int T = ldx >> 6;                 // 32 K-steps
        for (int t = 0; t < T; ++t) {
            const int kt = t * 64;
#pragma unroll
            for (int it = 0; it < 4; ++it) {
                const int c = wave * 4 + it;
                const int row = c * 8 + srow8;
                const size_t go = (size_t)row * ldx + kt + gslot * 8;
                gld_lds16(Ab + go, &sm[0][c * 512]);
                gld_lds16(Bb + go, &sm[1][c * 512]);
            }
            __syncthreads();

            f16x8 a[2][4], b[2][4];
#pragma unroll
            for (int ks = 0; ks < 2; ++ks)
#pragma unroll
                for (int i = 0; i < 4; ++i) {
                    const int ra = wr * 64 + i * 16 + mrow;
                    const int rb = wc * 64 + i * 16 + mrow;
                    const int sa = ((q + 4 * ks) ^ (mrow & 7)) * 8;
                    a[ks][i] = *(const f16x8*)&sm[0][ra * 64 + sa];
                    b[ks][i] = *(const f16x8*)&sm[1][rb * 64 + sa];
                }
#pragma unroll
            for (int i = 0; i < 4; ++i)
#pragma unroll
                for (int j = 0; j < 4; ++j) {
                    acc[i][j] = __builtin_amdgcn_mfma_f32_16x16x32_f16(
                        a[0][i], b[0][j], acc[i][j], 0, 0, 0);
                    acc[i][j] = __builtin_amdgcn_mfma_f32_16x16x32_f16(
                        a[1][i], b[1][j], acc[i][j], 0, 0, 0);
                }
            __syncthreads();
        }

        const bool isbf = (*dflag != 0);
        const float tau = isbf ? -1.0f : MTAU;   // bf16->f16 exact: no fixup

        // ---- epilogue: sign tile + borderline fixup + masked P writes ----
        u8* sgn = (u8*)sm;                        // 128 x 132 = 16896 B
        u32* list = (u32*)((u8*)sm + 24576);      // MAXFIX u32
        int* cntp = (int*)((u8*)sm + 28672);

        if (tid == 0) *cntp = 0;
#pragma unroll
        for (int i = 0; i < 4; ++i)
#pragma unroll
            for (int j = 0; j < 4; ++j)
#pragma unroll
                for (int r = 0; r < 4; ++r) {
                    const int rl = wr * 64 + i * 16 + q * 4 + r;
                    const int cl = wc * 64 + j * 16 + mrow;
                    const float v = acc[i][j][r];
                    sgn[rl * 132 + cl] = v > 0.f ? (u8)1
                                       : (v < 0.f ? (u8)2 : (u8)0);
                }
        __syncthreads();

#pragma unroll
        for (int i = 0; i < 4; ++i)
#pragma unroll
            for (int j = 0; j < 4; ++j)
#pragma unroll
                for (int r = 0; r < 4; ++r)
                    if (__builtin_fabsf(acc[i][j][r]) < tau) {
                        const int rl = wr * 64 + i * 16 + q * 4 + r;
                        const int cl = wc * 64 + j * 16 + mrow;
                        const int ix = atomicAdd(cntp, 1);
                        if (ix < MAXFIX) list[ix] = (u32)((rl << 8) | cl);
                    }
        __syncthreads();

        const int nfix = (*cntp < MAXFIX) ? *cntp : MAXFIX;
        for (int e = wave; e < nfix; e += 4) {
            const u32 pk = list[e];
            const int rl = (int)(pk >> 8), cl = (int)(pk & 255u);
            const u16* arh = Xhi + (size_t)(bm * 128 + rl) * ldx;
            const u16* arl = Xlo + (size_t)(bm * 128 + rl) * ldx;
            const u16* brh = Xhi + (size_t)(bn * 128 + cl) * ldx;
            const u16* brl = Xlo + (size_t)(bn * 128 + cl) * ldx;
            float ssum = 0.f;
#pragma unroll
            for (int kk = 0; kk < 4; ++kk) {
                const int k = kk * 512 + lane * 8;
                const f16x8 vah = *(const f16x8*)&arh[k];
                const f16x8 val2 = *(const f16x8*)&arl[k];
                const f16x8 vbh = *(const f16x8*)&brh[k];
                const f16x8 vbl = *(const f16x8*)&brl[k];
#pragma unroll
                for (int u = 0; u < 8; ++u)
                    ssum += ((float)vah[u] + (float)val2[u]) *
                            ((float)vbh[u] + (float)vbl[u]);
            }
#pragma unroll
            for (int o = 32; o > 0; o >>= 1) ssum += __shfl_xor(ssum, o, 64);
            if (lane == 0)
                sgn[rl * 132 + cl] = ssum > 0.f ? (u8)1
                                   : (ssum < 0.f ? (u8)2 : (u8)0);
        }
        __syncthreads();

        // normal orientation: ushort4 writes; adj sign from 2-bit map
        {
            const int c0 = (tid & 31) * 4;
            const int r0 = tid >> 5;          // 0..7
#pragma unroll
            for (int s = 0; s < 16; ++s) {
                const int rr = r0 + 8 * s;
                const size_t aidx = (size_t)(bm * 128 + rr) * N + bn * 128 + c0;
                const u8 ab = asgn[aidx >> 2];
                const u32 sw = *(const u32*)&sgn[rr * 132 + c0];
                ushort4 ov;
                ov.x = ((sw         & 0xFF) & (u32)(ab        & 3)) ? (u16)1 : (u16)0;
                ov.y = (((sw >>  8) & 0xFF) & (u32)((ab >> 2) & 3)) ? (u16)1 : (u16)0;
                ov.z = (((sw >> 16) & 0xFF) & (u32)((ab >> 4) & 3)) ? (u16)1 : (u16)0;
                ov.w = (((sw >> 24) & 0xFF) & (u32)((ab >> 6) & 3)) ? (u16)1 : (u16)0;
                *(ushort4*)&P[aidx] = ov;
            }
        }

        if (bm != bn) {
            // transposed orientation: sign tile read transposed, map direct
            const int b0 = (tid & 31) * 4;
            const int a0 = tid >> 5;
#pragma unroll
            for (int s = 0; s < 16; ++s) {
                const int a = a0 + 8 * s;
                const size_t aidx = (size_t)(bn * 128 + a) * N + bm * 128 + b0;
                const u8 ab = asgn[aidx >> 2];
                ushort4 ov;
                u16* op = &ov.x;
#pragma unroll
                for (int j = 0; j < 4; ++j) {
                    const u8 s3 = sgn[(b0 + j) * 132 + a];
                    op[j] = (u16)((s3 & ((ab >> (2 * j)) & 3)) ? 1 : 0);
                }
                *(ushort4*)&P[aidx] = ov;
            }
        }
    } else {
        // ---- h = x @ W (NT against WT) ----
        const int j = bid - NMASK;
        const int bn = j & 15;    // D/128 = 16
        const int bm = j >> 4;    // N/128 = 32

        const u16* Ab = Xhi + (size_t)bm * 128 * ldx;
        const u16* Bb = WT + (size_t)bn * 128 * D;

        f32x4 acc[4][4] = {};

        const int T = D >> 6;
        for (int t = 0; t < T; ++t) {
            const int kt = t * 64;
#pragma unroll
            for (int it = 0; it < 4; ++it) {
                const int c = wave * 4 + it;
                const int row = c * 8 + srow8;
                gld_lds16(Ab + (size_t)row * ldx + kt + gslot * 8,
                          &sm[0][c * 512]);
                gld_lds16(Bb + (size_t)row * D + kt + gslot * 8,
                          &sm[1][c * 512]);
            }
            __syncthreads();

            f16x8 a[2][4], b[2][4];
#pragma unroll
            for (int ks = 0; ks < 2; ++ks)
#pragma unroll
                for (int i = 0; i < 4; ++i) {
                    const int ra = wr * 64 + i * 16 + mrow;
                    const int rb = wc * 64 + i * 16 + mrow;
                    const int sa = ((q + 4 * ks) ^ (mrow & 7)) * 8;
                    a[ks][i] = *(const f16x8*)&sm[0][ra * 64 + sa];
                    b[ks][i] = *(const f16x8*)&sm[1][rb * 64 + sa];
                }
#pragma unroll
            for (int i = 0; i < 4; ++i)
#pragma unroll
                for (int jj = 0; jj < 4; ++jj) {
                    acc[i][jj] = __builtin_amdgcn_mfma_f32_16x16x32_f16(
                        a[0][i], b[0][jj], acc[i][jj], 0, 0, 0);
                    acc[i][jj] = __builtin_amdgcn_mfma_f32_16x16x32_f16(
                        a[1][i], b[1][jj], acc[i][jj], 0, 0, 0);
                }
            __syncthreads();
        }

        const int row0 = bm * 128 + wr * 64 + q * 4;
        const int col0 = bn * 128 + wc * 64 + mrow;
#pragma unroll
        for (int i = 0; i < 4; ++i)
#pragma unroll
            for (int jj = 0; jj < 4; ++jj)
#pragma unroll
                for (int r = 0; r < 4; ++r)
                    h[(size_t)(row0 + i * 16 + r) * D + col0 + jj * 16] =
                        f2h(acc[i][jj][r]);
    }
}

// ==== merged post1: blocks [0,N) s1s2 rows; [N, N+2048) h->hT transpose ====
__global__ __launch_bounds__(256) void post1_kernel(
    const u16* __restrict__ h, const u16* __restrict__ a,
    float* __restrict__ s1, float* __restrict__ s2,
    u16* __restrict__ hT, int N, int D)
{
    __shared__ u16 tile[64][68];
    __shared__ float r1[4], r2[4];
    const int b = blockIdx.x;
    const int t = threadIdx.x;

    if (b < N) {
        const u16* hr = h + (size_t)b * D;
        const int k0 = t * 8;
        float acc1 = 0.f, acc2 = 0.f;
#pragma unroll
        for (int u = 0; u < 8; u += 4) {
            ushort4 hv  = *(const ushort4*)&hr[k0 + u];
            ushort4 a1v = *(const ushort4*)&a[k0 + u];
            ushort4 a2v = *(const ushort4*)&a[D + k0 + u];
            acc1 += h2f(hv.x) * h2f(a1v.x) + h2f(hv.y) * h2f(a1v.y)
                  + h2f(hv.z) * h2f(a1v.z) + h2f(hv.w) * h2f(a1v.w);
            acc2 += h2f(hv.x) * h2f(a2v.x) + h2f(hv.y) * h2f(a2v.y)
                  + h2f(hv.z) * h2f(a2v.z) + h2f(hv.w) * h2f(a2v.w);
        }
        const int lane = t & 63, wv = t >> 6;
#pragma unroll
        for (int o = 32; o > 0; o >>= 1) {
            acc1 += __shfl_down(acc1, o, 64);
            acc2 += __shfl_down(acc2, o, 64);
        }
        if (lane == 0) { r1[wv] = acc1; r2[wv] = acc2; }
        __syncthreads();
        if (t == 0) {
            s1[b] = r1[0] + r1[1] + r1[2] + r1[3];
            s2[b] = r2[0] + r2[1] + r2[2] + r2[3];
        }
    } else {
        const int tt = b - N;
        const int bc = (tt & 31) * 64;
        const int br = (tt >> 5) * 64;
        const int lr = t >> 4;
        const int lc = (t & 15) * 4;
#pragma unroll
        for (int s = 0; s < 4; ++s) {
            const int r = lr + s * 16;
            ushort4 v = *(const ushort4*)&h[(size_t)(br + r) * D + bc + lc];
            tile[r][lc + 0] = v.x; tile[r][lc + 1] = v.y;
            tile[r][lc + 2] = v.z; tile[r][lc + 3] = v.w;
        }
        __syncthreads();
#pragma unroll
        for (int s = 0; s < 4; ++s) {
            const int oc = lr + s * 16;
            ushort4 v;
            v.x = tile[lc + 0][oc]; v.y = tile[lc + 1][oc];
            v.z = tile[lc + 2][oc]; v.w = tile[lc + 3][oc];
            *(ushort4*)&hT[(size_t)(bc + oc) * N + br + lc] = v;
        }
    }
}

// ---- row softmax: P flags in, f16 probs out ----
__global__ __launch_bounds__(256) void softmax_kernel(
    u16* __restrict__ P, const float* __restrict__ s1,
    const float* __restrict__ s2, int N)
{
    const int row = blockIdx.x;
    const int t = threadIdx.x;
    const int lane = t & 63, wv = t >> 6;
    u16* prow = P + (size_t)row * N;
    const float s1v = s1[row];

    float e[16];
#pragma unroll
    for (int it = 0; it < 16; ++it) {
        const int j = it * 256 + t;
        const u16 f = prow[j];
        float ev = s1v + s2[j];
        ev = ev >= 0.f ? ev : 0.1f * ev;
        e[it] = f ? ev : -9.0e15f;
    }
    float m = -3.4e38f;
#pragma unroll
    for (int it = 0; it < 16; ++it) m = fmaxf(m, e[it]);
#pragma unroll
    for (int o = 32; o > 0; o >>= 1) m = fmaxf(m, __shfl_xor(m, o, 64));
    __shared__ float red[8];
    if (lane == 0) red[wv] = m;
    __syncthreads();
    m = fmaxf(fmaxf(red[0], red[1]), fmaxf(red[2], red[3]));

    float sum = 0.f;
#pragma unroll
    for (int it = 0; it < 16; ++it) {
        e[it] = expf(fminf(e[it] - m, 0.0f));
        sum += e[it];
    }
#pragma unroll
    for (int o = 32; o > 0; o >>= 1) sum += __shfl_xor(sum, o, 64);
    if (lane == 0) red[4 + wv] = sum;
    __syncthreads();
    sum = red[4] + red[5] + red[6] + red[7];
    const float inv = 1.f / fmaxf(sum, 1e-30f);
#pragma unroll
    for (int it = 0; it < 16; ++it) {
        const int j = it * 256 + t;
        prow[j] = f2h(e[it] * inv);
    }
}

// ==== out = elu(P @ hT^T): 128x128 tiles, grid (16,32), BK=64 single-buffered
// 32 KB LDS, conflict-free swizzle — byte-exact R4. ====
__global__ __launch_bounds__(256, 2) void gemm_elu(
    const u16* __restrict__ A, int lda,   // P: N x N (f16 probs)
    const u16* __restrict__ B, int ldb,   // hT: D x N
    u16* __restrict__ C, int ldc,         // out: N x D
    int K, const u32* __restrict__ dflag)
{
    __shared__ alignas(16) u16 sm[2][128 * 64];   // 32 KB

    const int tid = threadIdx.x;
    const int wave = tid >> 6, lane = tid & 63;
    const int wr = wave >> 1, wc = wave & 1;
    const int q = lane >> 4, mrow = lane & 15;
    const int srow8 = lane >> 3;
    const int gslot = (lane & 7) ^ srow8;

    const int bm = blockIdx.y;   // N/128 = 32
    const int bn = blockIdx.x;   // D/128 = 16

    const u16* Ab = A + (size_t)bm * 128 * lda;
    const u16* Bb = B + (size_t)bn * 128 * ldb;

    f32x4 acc[4][4] = {};

    const int T = K >> 6;    // 64 steps
    for (int t = 0; t < T; ++t) {
        const int kt = t * 64;
#pragma unroll
        for (int it = 0; it < 4; ++it) {
            const int c = wave * 4 + it;
            const int row = c * 8 + srow8;
            gld_lds16(Ab + (size_t)row * lda + kt + gslot * 8, &sm[0][c * 512]);
            gld_lds16(Bb + (size_t)row * ldb + kt + gslot * 8, &sm[1][c * 512]);
        }
        __syncthreads();

        f16x8 a[2][4], b[2][4];
#pragma unroll
        for (int ks = 0; ks < 2; ++ks)
#pragma unroll
            for (int i = 0; i < 4; ++i) {
                const int ra = wr * 64 + i * 16 + mrow;
                const int rb = wc * 64 + i * 16 + mrow;
                const int sa = ((q + 4 * ks) ^ (mrow & 7)) * 8;
                a[ks][i] = *(const f16x8*)&sm[0][ra * 64 + sa];
                b[ks][i] = *(const f16x8*)&sm[1][rb * 64 + sa];
            }
#pragma unroll
        for (int i = 0; i < 4; ++i)
#pragma unroll
            for (int j = 0; j < 4; ++j) {
                acc[i][j] = __builtin_amdgcn_mfma_f32_16x16x32_f16(
                    a[0][i], b[0][j], acc[i][j], 0, 0, 0);
                acc[i][j] = __builtin_amdgcn_mfma_f32_16x16x32_f16(
                    a[1][i], b[1][j], acc[i][j], 0, 0, 0);
            }
        __syncthreads();
    }

    const bool isbf = (*dflag != 0);
    float* outF = (float*)C;
    const int row0 = bm * 128 + wr * 64 + q * 4;
    const int col0 = bn * 128 + wc * 64 + mrow;
#pragma unroll
    for (int i = 0; i < 4; ++i)
#pragma unroll
        for (int j = 0; j < 4; ++j)
#pragma unroll
            for (int r = 0; r < 4; ++r) {
                const int row = row0 + i * 16 + r;
                const int col = col0 + j * 16;
                const float v = acc[i][j][r];
                const float o = v > 0.0f ? v : expm1f(v);
                if (isbf) C[(size_t)row * ldc + col] = f2bf(o);
                else      outF[(size_t)row * ldc + col] = o;
            }
}

extern "C" void kernel_launch(void* const* d_in, const int* in_sizes, int n_in,
                              void* d_out, int out_size, void* d_ws, size_t ws_size,
                              hipStream_t stream)
{
    const void* x   = d_in[0];   // 4096 x 2048 (fp32 or bf16 — sniffed)
    const void* adj = d_in[1];   // 4096 x 4096
    const void* W   = d_in[2];   // 2048 x 2048
    const void* a   = d_in[3];   // 4096

    const int N = 4096, D = 2048;

    u16* xhi = (u16*)d_ws;                       // N*D f16
    u16* xlo = xhi + (size_t)N * D;              // N*D f16 (later reused as hT)
    u16* WT  = xlo + (size_t)N * D;              // D*D f16
    u16* h   = WT  + (size_t)D * D;              // N*D f16
    u16* P   = h   + (size_t)N * D;              // N*N (flags, then f16 probs)
    u16* af  = P   + (size_t)N * N;              // 4096 f16
    float* s1 = (float*)(af + 4096);
    float* s2 = s1 + N;
    u32* flag = (u32*)(s2 + N);
    u8* asgn = (u8*)(flag + 16);                 // N*N/4 bytes = 4 MB, 2-bit map

    // 0. dtype sniff
    sniff_kernel<<<1, 256, 0, stream>>>((const u16*)x, flag);
    // 1. merged converts (split + WT + a + adj sign map)
    prep_kernel<<<dim3(3073), 256, 0, stream>>>(x, W, a, adj, xhi, xlo, WT, af,
                                                asgn, flag, N, D);
    // 2. fused: triangle mask (528) + h = x@W (512), R4 loop + map epilogue
    fused_mask_h<<<dim3(1040), 256, 0, stream>>>(
        xhi, xlo, D, P, N, asgn, WT, D, h, flag);
    // 3. merged s1s2 (4096) + h->hT transpose (2048) (hT into xlo)
    post1_kernel<<<dim3(N + 2048), 256, 0, stream>>>(h, af, s1, s2, xlo, N, D);
    // 4. softmax rows -> P probs (f16)
    softmax_kernel<<<dim3(N), 256, 0, stream>>>(P, s1, s2, N);
    // 5. out = elu(P @ h), R4 loop
    gemm_elu<<<dim3(D / 128, N / 128), 256, 0, stream>>>(
        P, N, xlo, N, (u16*)d_out, D, N, flag);
}